// Round 12
// baseline (1753.777 us; speedup 1.0000x reference)
//
#include <hip/hip_runtime.h>
#include <hip/hip_cooperative_groups.h>

typedef unsigned short u16;
typedef unsigned int   u32;
typedef __attribute__((ext_vector_type(8))) short short8;
typedef __attribute__((ext_vector_type(4))) float f32x4;

typedef __attribute__((address_space(1))) const void GASV;
typedef __attribute__((address_space(3))) void LASV;

#define IMG_BYTES  557568      /* 66*66*64*2 (padded bf16 image) */
#define WS_SCALE   0
#define WS_SHIFT   256
#define WS_PART    512
#define WS_WA      8704                      /* 54 (27st x 2oh) * 12288 B = 663552 */
#define WS_BNXP    672256                    /* 64 * IMG_BYTES */
#define WS_HC      (WS_BNXP + (size_t)64*IMG_BYTES)   /* 4 pads x 4*IMG_BYTES */

/* k_steps dynamic LDS: 4 input rows (66 cells x 144 B) + 4-deep weight ring */
#define SM_RING_OFF 38016
#define SMEM_TOT    (38016 + 4*12288)        /* 87168 B -> 1 block/CU */

__device__ __forceinline__ u16 f2b(float f){
  u32 x = __float_as_uint(f);
  return (u16)((x + 0x7fffu + ((x>>16)&1u)) >> 16);
}
__device__ __forceinline__ float sigm(float x){ return 1.f/(1.f+__expf(-x)); }
__device__ __forceinline__ float tanh_(float x){
  float e = __expf(2.f*fabsf(x));
  float t = 1.f - 2.f/(e+1.f);
  return copysignf(t, x);
}

/* ---- weight transform: f32 [O][C][3][3] -> per-(stage,oh) contiguous bf16 ----
   u16 idx = (stage*2+oh)*6144 + (cc*6+gate*2+og2)*512 + lane*8 + e
   och = gate*64 + (oh*2+og2)*16 + (lane&15) ; c = cc*32 + (lane>>4)*8 + e
   stage = j*9+tap, j: 0=conv1 1=c2h 2=h2h */
__global__ void k_wt(const float* __restrict__ c1, const float* __restrict__ c2h,
                     const float* __restrict__ h2h, u16* __restrict__ wA){
  int idx = blockIdx.x*256 + threadIdx.x;   /* 1296*256 = 331776 exact */
  int e = idx & 7;
  int lane = (idx >> 3) & 63;
  int v = idx >> 9;
  int f2 = v % 12;  v /= 12;
  int oh = v & 1;
  int stage = v >> 1;                       /* 0..26 */
  int cc = f2 / 6, gate = (f2 % 6) >> 1, og2 = f2 & 1;
  int j = stage / 9, tap = stage % 9;
  int och = gate*64 + (oh*2 + og2)*16 + (lane & 15);
  int c = cc*32 + (lane >> 4)*8 + e;
  const float* src = (j==0) ? c1 : ((j==1) ? c2h : h2h);
  wA[idx] = f2b(src[(och*64 + c)*9 + tap]);
}

/* ---- BN partial sums ---- */
__global__ void k_bnsum(const float* __restrict__ x, float* __restrict__ part){
  int c = blockIdx.x & 63, g = blockIdx.x >> 6;
  int tid = threadIdx.x, w = tid >> 6, lane = tid & 63;
  float s = 0.f, s2 = 0.f;
  for (int im = 0; im < 4; ++im){
    const float* base = x + (((size_t)((g*4+im)*64 + c)) << 12);
    #pragma unroll
    for (int it = 0; it < 4; ++it){
      float4 v = *(const float4*)(base + (((it<<8) + tid) << 2));
      s  += v.x + v.y + v.z + v.w;
      s2 += v.x*v.x + v.y*v.y + v.z*v.z + v.w*v.w;
    }
  }
  #pragma unroll
  for (int off = 32; off > 0; off >>= 1){
    s  += __shfl_down(s,  off);
    s2 += __shfl_down(s2, off);
  }
  __shared__ float red[8];
  if (lane == 0){ red[w] = s; red[4+w] = s2; }
  __syncthreads();
  if (tid == 0){
    part[(g<<7) + c] = red[0]+red[1]+red[2]+red[3];
    part[(g<<7) + 64 + c] = red[4]+red[5]+red[6]+red[7];
  }
}

__global__ void k_bnfin(const float* __restrict__ part, const float* __restrict__ gamma,
                        const float* __restrict__ beta, float* __restrict__ scale,
                        float* __restrict__ shift){
  int c = threadIdx.x;
  float S = 0.f, S2 = 0.f;
  for (int g = 0; g < 16; ++g){ S += part[(g<<7)+c]; S2 += part[(g<<7)+64+c]; }
  const float inv = 1.f/262144.f;
  float mean = S*inv;
  float var  = S2*inv - mean*mean;
  float sc = gamma[c] * rsqrtf(var + 1e-5f);
  scale[c] = sc;
  shift[c] = beta[c] - mean*sc;
}

/* ---- BN apply -> padded bf16 [img][66][66][64]; self-haloed ---- */
__global__ void k_bnx(const float* __restrict__ x, const float* __restrict__ scale,
                      const float* __restrict__ shift, char* __restrict__ bnxp){
  int img = blockIdx.x / 66, rp = blockIdx.x % 66;
  int tid = threadIdx.x;
  char* dstrow = bnxp + (size_t)img*IMG_BYTES + (size_t)rp*8448;
  const uint4 z = {0,0,0,0};
  if (rp == 0 || rp == 65){
    for (int i = tid; i < 528; i += 256) ((uint4*)dstrow)[i] = z;
    return;
  }
  if (tid < 16)
    *(uint4*)(dstrow + (tid>>3)*(65*128) + (tid&7)*16) = z;
  int r = rp - 1;
  int col = tid & 63, cq = tid >> 6;
  const float* xb = x + (((size_t)(img*64 + cq*16)) << 12) + (r<<6) + col;
  union { u16 u[16]; uint4 v[2]; } pk;
  #pragma unroll
  for (int i = 0; i < 16; ++i){
    int c = cq*16 + i;
    pk.u[i] = f2b(xb[((size_t)i) << 12]*scale[c] + shift[c]);
  }
  char* dst = dstrow + (size_t)(col + 1)*128 + cq*32;
  *(uint4*)dst = pk.v[0];
  *(uint4*)(dst+16) = pk.v[1];
}

/* ---- persistent cooperative ConvLSTM: all 16 steps in ONE kernel.
        256 blocks (1/CU) x 512 thr = 8 waves (wr, og2, ch).
        Block = (n, row-pair rp, och-half oh) fixed for all t.
        c-state in registers for the whole sequence. grid.sync() between
        steps gives device-scope h/c pad visibility (per-XCD L2, G16). ---- */
#define STAGE_W(v) do {                                                         \
  if (w < 4){                                                                   \
    int _vj = jp + (v)/9; if (_vj >= 3) _vj -= 3;                               \
    int _vt = tp + (v)%9; if (_vt >= 9) _vt -= 9;                               \
    const char* _gs = wA + ((size_t)((_vj*9 + _vt)*2 + oh))*12288               \
                        + w*3072 + lane*16;                                     \
    char* _ls = smem + SM_RING_OFF + ((v)&3)*12288 + w*3072;                    \
    __builtin_amdgcn_global_load_lds((GASV*)(_gs),        (LASV*)(_ls),        16, 0, 0); \
    __builtin_amdgcn_global_load_lds((GASV*)(_gs + 1024), (LASV*)(_ls + 1024), 16, 0, 0); \
    __builtin_amdgcn_global_load_lds((GASV*)(_gs + 2048), (LASV*)(_ls + 2048), 16, 0, 0); \
  }                                                                             \
} while(0)

#define WAITN_BAR(N) do {                                                       \
  asm volatile("s_waitcnt vmcnt(" #N ")\n\ts_barrier" ::: "memory");            \
  __builtin_amdgcn_sched_barrier(0);                                            \
} while(0)

__global__ __launch_bounds__(512, 1) void k_steps(
    const char* __restrict__ bnxp,
    char* __restrict__ cpad0, char* __restrict__ hpad0,
    char* __restrict__ cpad1, char* __restrict__ hpad1,
    const char* __restrict__ wA, const float* __restrict__ b1,
    float* __restrict__ out)
{
  extern __shared__ __align__(16) char smem[];
  cooperative_groups::grid_group grid = cooperative_groups::this_grid();
  const int tid = threadIdx.x;
  const int w = tid >> 6, lane = tid & 63;
  const int l15 = lane & 15, l4 = lane >> 4;
  const int wr = w >> 2, og2 = (w >> 1) & 1, ch = w & 1;
  const int bid = blockIdx.x;
  const int oh = bid & 1, rp = (bid >> 1) & 31, n = bid >> 6;
  const int jp = bid % 3, tp = bid % 9;

  const int gc0 = ((oh<<1) + og2)*16 + l4*4;
  float bv[12];
  #pragma unroll
  for (int reg = 0; reg < 4; ++reg){
    bv[reg]   = b1[gc0+reg];
    bv[4+reg] = b1[64+gc0+reg];
    bv[8+reg] = b1[128+gc0+reg];
  }
  float cpv[8];
  #pragma unroll
  for (int i = 0; i < 8; ++i) cpv[i] = 0.f;

  const int r = (rp << 1) + wr;

  for (int t = 0; t < 16; ++t){
    const char* cpad_s = (t & 1) ? cpad1 : cpad0;
    const char* hpad_s = (t & 1) ? hpad1 : hpad0;
    char* cpad_d = (t & 1) ? cpad0 : cpad1;
    char* hpad_d = (t & 1) ? hpad0 : hpad1;
    const char* gb0 = bnxp   + (size_t)(t*4+n)*IMG_BYTES + rp*16896;
    const char* gb1 = cpad_s + (size_t)n*IMG_BYTES + rp*16896;
    const char* gb2 = hpad_s + (size_t)n*IMG_BYTES + rp*16896;

    f32x4 acc[3][2];
    #pragma unroll
    for (int a = 0; a < 3; ++a)
      #pragma unroll
      for (int b = 0; b < 2; ++b)
        acc[a][b] = (f32x4){0.f,0.f,0.f,0.f};

    STAGE_W(0); STAGE_W(1); STAGE_W(2);

    #pragma unroll
    for (int jj = 0; jj < 3; ++jj){
      int jv = jp + jj; if (jv >= 3) jv -= 3;
      const char* gbj = (jv==0) ? gb0 : ((jv==1) ? gb1 : gb2);
      for (int i = tid; i < 2112; i += 512){
        int rr = i / 528, iw = i % 528;
        *(uint4*)(smem + rr*9504 + (iw>>3)*144 + (iw&7)*16) =
            *(const uint4*)(gbj + rr*8448 + iw*16);
      }
      __syncthreads();   /* drains vmcnt + lgkmcnt; stages to date resident */

      #pragma unroll
      for (int tt = 0; tt < 9; ++tt){
        const int u = jj*9 + tt;
        if (u <= 23) STAGE_W(u+3);
        {
          int tv = tp + tt; if (tv >= 9) tv -= 9;
          const int kh = tv/3, kw = tv - kh*3;
          const char* ab0 = smem + SM_RING_OFF + (u&3)*12288 + og2*1024 + lane*16;
          const char* ib0 = smem + (wr + kh)*9504 + ((ch<<5) + kw + l15)*144 + (l4<<4);
          #pragma unroll
          for (int cc = 0; cc < 2; ++cc){
            short8 af = *(const short8*)(ab0 + cc*6144);
            short8 ao = *(const short8*)(ab0 + cc*6144 + 2048);
            short8 ag = *(const short8*)(ab0 + cc*6144 + 4096);
            #pragma unroll
            for (int cf = 0; cf < 2; ++cf){
              short8 bf = *(const short8*)(ib0 + (cf<<4)*144 + (cc<<6));
              acc[0][cf] = __builtin_amdgcn_mfma_f32_16x16x32_bf16(af, bf, acc[0][cf], 0,0,0);
              acc[1][cf] = __builtin_amdgcn_mfma_f32_16x16x32_bf16(ao, bf, acc[1][cf], 0,0,0);
              acc[2][cf] = __builtin_amdgcn_mfma_f32_16x16x32_bf16(ag, bf, acc[2][cf], 0,0,0);
            }
          }
        }
        if (u <= 23)      WAITN_BAR(6);
        else if (u == 24) WAITN_BAR(3);
        else if (u == 25) WAITN_BAR(0);
        /* u == 26: last compute, falls through to epilogue */
      }
    }

    /* epilogue: gates with register-resident c; write out + bf16 h/c pads */
    const size_t ob = ((size_t)((t*4+n)*64)) << 12;
    char* hrow = hpad_d + (size_t)n*IMG_BYTES + (size_t)(r+1)*8448;
    char* crow = cpad_d + (size_t)n*IMG_BYTES + (size_t)(r+1)*8448;

    #pragma unroll
    for (int cf = 0; cf < 2; ++cf){
      const int col = (ch<<5) + (cf<<4) + l15;
      const int p = (r<<6) + col;
      union { u16 u[4]; uint2 v; } hp, cp2;
      #pragma unroll
      for (int reg = 0; reg < 4; ++reg){
        const int gc = gc0 + reg;
        float f  = sigm(acc[0][cf][reg] + bv[reg]);
        float og_ = sigm(acc[1][cf][reg] + bv[4+reg]);
        float g  = tanh_(acc[2][cf][reg] + bv[8+reg]);
        float cn = f*cpv[cf*4+reg] + (1.f-f)*g;
        float hn = og_ * tanh_(cn);
        cpv[cf*4+reg] = cn;
        out[ob + (((size_t)gc)<<12) + p] = hn;
        hp.u[reg]  = f2b(hn);
        cp2.u[reg] = f2b(cn);
      }
      *(uint2*)(hrow + (size_t)(col+1)*128 + gc0*2) = hp.v;
      *(uint2*)(crow + (size_t)(col+1)*128 + gc0*2) = cp2.v;
    }

    if (t < 15){
      __threadfence();   /* device-scope release of pad writes */
      grid.sync();       /* all blocks' step-t reads+writes complete */
    }
  }
}

extern "C" void kernel_launch(void* const* d_in, const int* in_sizes, int n_in,
                              void* d_out, int out_size, void* d_ws, size_t ws_size,
                              hipStream_t stream)
{
  (void)in_sizes; (void)n_in; (void)out_size; (void)ws_size;
  const float* x     = (const float*)d_in[0];
  const float* gamma = (const float*)d_in[1];
  const float* beta  = (const float*)d_in[2];
  const float* c1w   = (const float*)d_in[3];
  const float* c1b   = (const float*)d_in[4];
  const float* wh2h  = (const float*)d_in[5];
  const float* wc2h  = (const float*)d_in[6];
  char* ws  = (char*)d_ws;
  float* out = (float*)d_out;

  hipFuncSetAttribute(reinterpret_cast<const void*>(k_steps),
                      hipFuncAttributeMaxDynamicSharedMemorySize, SMEM_TOT);

  char* hpad0 = ws + WS_HC;
  char* cpad0 = ws + WS_HC + (size_t)4*IMG_BYTES;
  char* hpad1 = ws + WS_HC + (size_t)8*IMG_BYTES;
  char* cpad1 = ws + WS_HC + (size_t)12*IMG_BYTES;

  /* zero h/c ping-pong (incl. halos) each call (graph-safe) */
  hipMemsetAsync(ws + WS_HC, 0, (size_t)16*IMG_BYTES, stream);

  k_wt<<<1296, 256, 0, stream>>>(c1w, wc2h, wh2h, (u16*)(ws + WS_WA));
  k_bnsum<<<1024, 256, 0, stream>>>(x, (float*)(ws + WS_PART));
  k_bnfin<<<1, 64, 0, stream>>>((const float*)(ws + WS_PART), gamma, beta,
                                (float*)(ws + WS_SCALE), (float*)(ws + WS_SHIFT));
  k_bnx<<<4224, 256, 0, stream>>>(x, (const float*)(ws + WS_SCALE),
                                  (const float*)(ws + WS_SHIFT), ws + WS_BNXP);

  const char* bnxp_p = ws + WS_BNXP;
  const char* wA_p   = ws + WS_WA;
  const float* b1_p  = c1b;
  float* out_p = out;
  void* args[] = { (void*)&bnxp_p, (void*)&cpad0, (void*)&hpad0,
                   (void*)&cpad1, (void*)&hpad1, (void*)&wA_p,
                   (void*)&b1_p, (void*)&out_p };
  hipLaunchCooperativeKernel(reinterpret_cast<const void*>(k_steps),
                             dim3(256), dim3(512), args, SMEM_TOT, stream);
}

// Round 13
// 363.744 us; speedup vs baseline: 4.8215x; 4.8215x over previous
//
#include <hip/hip_runtime.h>

typedef unsigned short u16;
typedef unsigned int   u32;
typedef __attribute__((ext_vector_type(8))) short short8;
typedef __attribute__((ext_vector_type(4))) float f32x4;

typedef __attribute__((address_space(1))) const void GASV;
typedef __attribute__((address_space(3))) void LASV;

#define IMG_BYTES  557568      /* 66*66*64*2 (padded bf16 image) */
#define WS_SCALE   0
#define WS_SHIFT   256
#define WS_PART    512
#define WS_WA      8704                      /* 54 (27st x 2oh) * 12288 B */
#define WS_BNXP    672256                    /* 64 * IMG_BYTES */
#define WS_HC      (WS_BNXP + (size_t)64*IMG_BYTES)
#define WS_CSTATE  (WS_HC + (size_t)16*IMG_BYTES)    /* 256*512*8 f32 = 4 MiB */

/* k_step dynamic LDS: 4 input rows (66 cells x 144 B) + 6-deep weight ring */
#define SM_RING_OFF 38016
#define SMEM_TOT    (38016 + 6*12288)        /* 111744 B -> 1 block/CU */

__device__ __forceinline__ u16 f2b(float f){
  u32 x = __float_as_uint(f);
  return (u16)((x + 0x7fffu + ((x>>16)&1u)) >> 16);
}
__device__ __forceinline__ float sigm(float x){ return 1.f/(1.f+__expf(-x)); }
__device__ __forceinline__ float tanh_(float x){
  float e = __expf(2.f*fabsf(x));
  float t = 1.f - 2.f/(e+1.f);
  return copysignf(t, x);
}

/* ---- weight transform: f32 [O][C][3][3] -> per-(stage,oh) contiguous bf16 ----
   u16 idx = (stage*2+oh)*6144 + (cc*6+gate*2+og2)*512 + lane*8 + e
   och = gate*64 + (oh*2+og2)*16 + (lane&15) ; c = cc*32 + (lane>>4)*8 + e */
__global__ void k_wt(const float* __restrict__ c1, const float* __restrict__ c2h,
                     const float* __restrict__ h2h, u16* __restrict__ wA){
  int idx = blockIdx.x*256 + threadIdx.x;   /* 1296*256 = 331776 exact */
  int e = idx & 7;
  int lane = (idx >> 3) & 63;
  int v = idx >> 9;
  int f2 = v % 12;  v /= 12;
  int oh = v & 1;
  int stage = v >> 1;
  int cc = f2 / 6, gate = (f2 % 6) >> 1, og2 = f2 & 1;
  int j = stage / 9, tap = stage % 9;
  int och = gate*64 + (oh*2 + og2)*16 + (lane & 15);
  int c = cc*32 + (lane >> 4)*8 + e;
  const float* src = (j==0) ? c1 : ((j==1) ? c2h : h2h);
  wA[idx] = f2b(src[(och*64 + c)*9 + tap]);
}

/* ---- BN partial sums ---- */
__global__ void k_bnsum(const float* __restrict__ x, float* __restrict__ part){
  int c = blockIdx.x & 63, g = blockIdx.x >> 6;
  int tid = threadIdx.x, w = tid >> 6, lane = tid & 63;
  float s = 0.f, s2 = 0.f;
  for (int im = 0; im < 4; ++im){
    const float* base = x + (((size_t)((g*4+im)*64 + c)) << 12);
    #pragma unroll
    for (int it = 0; it < 4; ++it){
      float4 v = *(const float4*)(base + (((it<<8) + tid) << 2));
      s  += v.x + v.y + v.z + v.w;
      s2 += v.x*v.x + v.y*v.y + v.z*v.z + v.w*v.w;
    }
  }
  #pragma unroll
  for (int off = 32; off > 0; off >>= 1){
    s  += __shfl_down(s,  off);
    s2 += __shfl_down(s2, off);
  }
  __shared__ float red[8];
  if (lane == 0){ red[w] = s; red[4+w] = s2; }
  __syncthreads();
  if (tid == 0){
    part[(g<<7) + c] = red[0]+red[1]+red[2]+red[3];
    part[(g<<7) + 64 + c] = red[4]+red[5]+red[6]+red[7];
  }
}

__global__ void k_bnfin(const float* __restrict__ part, const float* __restrict__ gamma,
                        const float* __restrict__ beta, float* __restrict__ scale,
                        float* __restrict__ shift){
  int c = threadIdx.x;
  float S = 0.f, S2 = 0.f;
  for (int g = 0; g < 16; ++g){ S += part[(g<<7)+c]; S2 += part[(g<<7)+64+c]; }
  const float inv = 1.f/262144.f;
  float mean = S*inv;
  float var  = S2*inv - mean*mean;
  float sc = gamma[c] * rsqrtf(var + 1e-5f);
  scale[c] = sc;
  shift[c] = beta[c] - mean*sc;
}

/* ---- BN apply -> padded bf16 [img][66][66][64]; self-haloed ---- */
__global__ void k_bnx(const float* __restrict__ x, const float* __restrict__ scale,
                      const float* __restrict__ shift, char* __restrict__ bnxp){
  int img = blockIdx.x / 66, rp = blockIdx.x % 66;
  int tid = threadIdx.x;
  char* dstrow = bnxp + (size_t)img*IMG_BYTES + (size_t)rp*8448;
  const uint4 z = {0,0,0,0};
  if (rp == 0 || rp == 65){
    for (int i = tid; i < 528; i += 256) ((uint4*)dstrow)[i] = z;
    return;
  }
  if (tid < 16)
    *(uint4*)(dstrow + (tid>>3)*(65*128) + (tid&7)*16) = z;
  int r = rp - 1;
  int col = tid & 63, cq = tid >> 6;
  const float* xb = x + (((size_t)(img*64 + cq*16)) << 12) + (r<<6) + col;
  union { u16 u[16]; uint4 v[2]; } pk;
  #pragma unroll
  for (int i = 0; i < 16; ++i){
    int c = cq*16 + i;
    pk.u[i] = f2b(xb[((size_t)i) << 12]*scale[c] + shift[c]);
  }
  char* dst = dstrow + (size_t)(col + 1)*128 + cq*32;
  *(uint4*)dst = pk.v[0];
  *(uint4*)(dst+16) = pk.v[1];
}

/* ---- fused ConvLSTM step: 256 blocks = (n, row-pair rp, oh). 512 thr =
        8 waves (wr, og2, ch). Weight DMA ring-6 via global_load_lds,
        PAIRED stages (2 computes per fused vmcnt+barrier), setprio around
        MFMA clusters, cstate in coalesced [bid][tid][8] f32 layout. ---- */
#define STAGE_W(v) do {                                                         \
  if ((v) <= 26 && w < 4){                                                      \
    int _vj = jp + (v)/9; if (_vj >= 3) _vj -= 3;                               \
    int _vt = tp + (v)%9; if (_vt >= 9) _vt -= 9;                               \
    const char* _gs = wA + ((size_t)((_vj*9 + _vt)*2 + oh))*12288               \
                        + w*3072 + lane*16;                                     \
    char* _ls = smem + SM_RING_OFF + ((v)%6)*12288 + w*3072;                    \
    __builtin_amdgcn_global_load_lds((GASV*)(_gs),        (LASV*)(_ls),        16, 0, 0); \
    __builtin_amdgcn_global_load_lds((GASV*)(_gs + 1024), (LASV*)(_ls + 1024), 16, 0, 0); \
    __builtin_amdgcn_global_load_lds((GASV*)(_gs + 2048), (LASV*)(_ls + 2048), 16, 0, 0); \
  }                                                                             \
} while(0)

#define WAITN_BAR(N) do {                                                       \
  asm volatile("s_waitcnt vmcnt(" #N ")\n\ts_barrier" ::: "memory");            \
  __builtin_amdgcn_sched_barrier(0);                                            \
} while(0)

#define COMPUTE(u) do {                                                         \
  int tv = tp + (u)%9; if (tv >= 9) tv -= 9;                                    \
  const int kh = tv/3, kw = tv - kh*3;                                          \
  const char* ab0 = smem + SM_RING_OFF + ((u)%6)*12288 + og2*1024 + lane*16;    \
  const char* ib0 = smem + (wr + kh)*9504 + ((ch<<5) + kw + l15)*144 + (l4<<4); \
  _Pragma("unroll")                                                             \
  for (int cc = 0; cc < 2; ++cc){                                               \
    short8 af = *(const short8*)(ab0 + cc*6144);                                \
    short8 ao = *(const short8*)(ab0 + cc*6144 + 2048);                         \
    short8 ag = *(const short8*)(ab0 + cc*6144 + 4096);                         \
    _Pragma("unroll")                                                           \
    for (int cf = 0; cf < 2; ++cf){                                             \
      short8 bf = *(const short8*)(ib0 + (cf<<4)*144 + (cc<<6));                \
      acc[0][cf] = __builtin_amdgcn_mfma_f32_16x16x32_bf16(af, bf, acc[0][cf], 0,0,0); \
      acc[1][cf] = __builtin_amdgcn_mfma_f32_16x16x32_bf16(ao, bf, acc[1][cf], 0,0,0); \
      acc[2][cf] = __builtin_amdgcn_mfma_f32_16x16x32_bf16(ag, bf, acc[2][cf], 0,0,0); \
    }                                                                           \
  }                                                                             \
} while(0)

__global__ __launch_bounds__(512, 1) void k_step(
    const char* __restrict__ bnxp,
    const char* __restrict__ cpad_s, const char* __restrict__ hpad_s,
    char* __restrict__ cpad_d, char* __restrict__ hpad_d,
    const char* __restrict__ wA, const float* __restrict__ b1,
    float* __restrict__ cstate, float* __restrict__ out, int t)
{
  extern __shared__ __align__(16) char smem[];
  const int tid = threadIdx.x;
  const int w = tid >> 6, lane = tid & 63;
  const int l15 = lane & 15, l4 = lane >> 4;
  const int wr = w >> 2, og2 = (w >> 1) & 1, ch = w & 1;
  const int bid = blockIdx.x;
  const int oh = bid & 1, rp = (bid >> 1) & 31, n = bid >> 6;
  const int jp = bid % 3, tp = bid % 9;

  const char* gb0 = bnxp   + (size_t)(t*4+n)*IMG_BYTES + rp*16896;
  const char* gb1 = cpad_s + (size_t)n*IMG_BYTES + rp*16896;
  const char* gb2 = hpad_s + (size_t)n*IMG_BYTES + rp*16896;

  /* cstate: coalesced [bid][tid][8] f32; t==0 -> zeros (skip poison read) */
  float* cslot = cstate + ((size_t)bid*512 + tid)*8;
  float cpv[8];
  if (t == 0){
    #pragma unroll
    for (int i = 0; i < 8; ++i) cpv[i] = 0.f;
  } else {
    f32x4 c0 = *(const f32x4*)cslot;
    f32x4 c1v = *(const f32x4*)(cslot + 4);
    cpv[0]=c0[0]; cpv[1]=c0[1]; cpv[2]=c0[2]; cpv[3]=c0[3];
    cpv[4]=c1v[0]; cpv[5]=c1v[1]; cpv[6]=c1v[2]; cpv[7]=c1v[3];
  }

  const int gc0 = ((oh<<1) + og2)*16 + l4*4;
  float bv[12];
  #pragma unroll
  for (int reg = 0; reg < 4; ++reg){
    bv[reg]   = b1[gc0+reg];
    bv[4+reg] = b1[64+gc0+reg];
    bv[8+reg] = b1[128+gc0+reg];
  }

  f32x4 acc[3][2];
  #pragma unroll
  for (int a = 0; a < 3; ++a)
    #pragma unroll
    for (int b = 0; b < 2; ++b)
      acc[a][b] = (f32x4){0.f,0.f,0.f,0.f};

  /* prologue: 4 weight stages in flight */
  STAGE_W(0); STAGE_W(1); STAGE_W(2); STAGE_W(3);

  #pragma unroll
  for (int jj = 0; jj < 3; ++jj){
    int jv = jp + jj; if (jv >= 3) jv -= 3;
    const char* gbj = (jv==0) ? gb0 : ((jv==1) ? gb1 : gb2);
    for (int i = tid; i < 2112; i += 512){
      int rr = i / 528, iw = i % 528;
      *(uint4*)(smem + rr*9504 + (iw>>3)*144 + (iw&7)*16) =
          *(const uint4*)(gbj + rr*8448 + iw*16);
    }
    __syncthreads();   /* drains vmcnt+lgkmcnt: all issued stages resident */

    /* 4 pairs + 1 single per conv; barrier per pair (fused counted vmcnt) */
    #pragma unroll
    for (int pp = 0; pp < 4; ++pp){
      const int u = jj*9 + 2*pp;
      STAGE_W(u+4); STAGE_W(u+5);
      __builtin_amdgcn_s_setprio(1);
      COMPUTE(u);
      COMPUTE(u+1);
      __builtin_amdgcn_s_setprio(0);
      if (u == 22)      WAITN_BAR(3);
      else if (u == 24) WAITN_BAR(0);
      else              WAITN_BAR(6);
    }
    {
      const int u = jj*9 + 8;
      STAGE_W(u+4);
      __builtin_amdgcn_s_setprio(1);
      COMPUTE(u);
      __builtin_amdgcn_s_setprio(0);
      /* jj<2: next conv's staging __syncthreads provides the barrier;
         jj==2: u==26 is the last compute, fall through to epilogue */
    }
  }

  /* epilogue: gates; coalesced cstate write; out + bf16 h/c pad writes */
  const int r = (rp << 1) + wr;
  const size_t ob = ((size_t)((t*4+n)*64)) << 12;
  char* hrow = hpad_d + (size_t)n*IMG_BYTES + (size_t)(r+1)*8448;
  char* crow = cpad_d + (size_t)n*IMG_BYTES + (size_t)(r+1)*8448;

  float cnew[8];
  #pragma unroll
  for (int cf = 0; cf < 2; ++cf){
    const int col = (ch<<5) + (cf<<4) + l15;
    const int p = (r<<6) + col;
    union { u16 u[4]; uint2 v; } hp, cp2;
    #pragma unroll
    for (int reg = 0; reg < 4; ++reg){
      const int gc = gc0 + reg;
      float f  = sigm(acc[0][cf][reg] + bv[reg]);
      float og_ = sigm(acc[1][cf][reg] + bv[4+reg]);
      float g  = tanh_(acc[2][cf][reg] + bv[8+reg]);
      float cn = f*cpv[cf*4+reg] + (1.f-f)*g;
      float hn = og_ * tanh_(cn);
      cnew[cf*4+reg] = cn;
      out[ob + (((size_t)gc)<<12) + p] = hn;
      hp.u[reg]  = f2b(hn);
      cp2.u[reg] = f2b(cn);
    }
    *(uint2*)(hrow + (size_t)(col+1)*128 + gc0*2) = hp.v;
    *(uint2*)(crow + (size_t)(col+1)*128 + gc0*2) = cp2.v;
  }
  *(f32x4*)cslot       = (f32x4){cnew[0],cnew[1],cnew[2],cnew[3]};
  *(f32x4*)(cslot + 4) = (f32x4){cnew[4],cnew[5],cnew[6],cnew[7]};
}

extern "C" void kernel_launch(void* const* d_in, const int* in_sizes, int n_in,
                              void* d_out, int out_size, void* d_ws, size_t ws_size,
                              hipStream_t stream)
{
  (void)in_sizes; (void)n_in; (void)out_size; (void)ws_size;
  const float* x     = (const float*)d_in[0];
  const float* gamma = (const float*)d_in[1];
  const float* beta  = (const float*)d_in[2];
  const float* c1w   = (const float*)d_in[3];
  const float* c1b   = (const float*)d_in[4];
  const float* wh2h  = (const float*)d_in[5];
  const float* wc2h  = (const float*)d_in[6];
  char* ws  = (char*)d_ws;
  float* out = (float*)d_out;

  hipFuncSetAttribute(reinterpret_cast<const void*>(k_step),
                      hipFuncAttributeMaxDynamicSharedMemorySize, SMEM_TOT);

  char* hpad0 = ws + WS_HC;
  char* cpad0 = ws + WS_HC + (size_t)4*IMG_BYTES;
  char* hpad1 = ws + WS_HC + (size_t)8*IMG_BYTES;
  char* cpad1 = ws + WS_HC + (size_t)12*IMG_BYTES;

  /* zero h/c ping-pong (halos + t0 state); cstate needs no memset (t0 branch) */
  hipMemsetAsync(ws + WS_HC, 0, (size_t)16*IMG_BYTES, stream);

  k_wt<<<1296, 256, 0, stream>>>(c1w, wc2h, wh2h, (u16*)(ws + WS_WA));
  k_bnsum<<<1024, 256, 0, stream>>>(x, (float*)(ws + WS_PART));
  k_bnfin<<<1, 64, 0, stream>>>((const float*)(ws + WS_PART), gamma, beta,
                                (float*)(ws + WS_SCALE), (float*)(ws + WS_SHIFT));
  k_bnx<<<4224, 256, 0, stream>>>(x, (const float*)(ws + WS_SCALE),
                                  (const float*)(ws + WS_SHIFT), ws + WS_BNXP);
  for (int t = 0; t < 16; ++t){
    const char* cs = (t & 1) ? cpad1 : cpad0;
    const char* hs = (t & 1) ? hpad1 : hpad0;
    char* cd = (t & 1) ? cpad0 : cpad1;
    char* hd = (t & 1) ? hpad0 : hpad1;
    k_step<<<256, 512, SMEM_TOT, stream>>>(ws + WS_BNXP, cs, hs, cd, hd,
                                           ws + WS_WA, c1b,
                                           (float*)(ws + WS_CSTATE), out, t);
  }
}

// Round 15
// 355.515 us; speedup vs baseline: 4.9331x; 1.0231x over previous
//
#include <hip/hip_runtime.h>

typedef unsigned short u16;
typedef unsigned int   u32;
typedef __attribute__((ext_vector_type(8))) short short8;
typedef __attribute__((ext_vector_type(4))) float f32x4;

typedef __attribute__((address_space(1))) const void GASV;
typedef __attribute__((address_space(3))) void LASV;

#define IMG_BYTES  557568      /* 66*66*64*2 (padded bf16 image) */
#define WS_SCALE   0
#define WS_SHIFT   256
#define WS_PART    512
#define WS_WA      8704                      /* 54 (27st x 2oh) * 12288 B */
#define WS_BNXP    672256                    /* 64 * IMG_BYTES */
#define WS_HC      (WS_BNXP + (size_t)64*IMG_BYTES)
#define WS_CSTATE  (WS_HC + (size_t)16*IMG_BYTES)    /* 256*512*8 f32 = 4 MiB */

/* k_step dynamic LDS: 4 input rows (66 cells x 128 B, XOR-swizzled chunks)
   + 6-deep weight ring */
#define SM_RING_OFF 33792                    /* 4 * 66 * 128 */
#define SMEM_TOT    (33792 + 6*12288)        /* 107520 B -> 1 block/CU */

__device__ __forceinline__ u16 f2b(float f){
  u32 x = __float_as_uint(f);
  return (u16)((x + 0x7fffu + ((x>>16)&1u)) >> 16);
}
__device__ __forceinline__ float sigm(float x){ return 1.f/(1.f+__expf(-x)); }
__device__ __forceinline__ float tanh_(float x){
  float e = __expf(2.f*fabsf(x));
  float t = 1.f - 2.f/(e+1.f);
  return copysignf(t, x);
}

/* ---- weight transform: f32 [O][C][3][3] -> per-(stage,oh) contiguous bf16 ---- */
__global__ void k_wt(const float* __restrict__ c1, const float* __restrict__ c2h,
                     const float* __restrict__ h2h, u16* __restrict__ wA){
  int idx = blockIdx.x*256 + threadIdx.x;   /* 1296*256 = 331776 exact */
  int e = idx & 7;
  int lane = (idx >> 3) & 63;
  int v = idx >> 9;
  int f2 = v % 12;  v /= 12;
  int oh = v & 1;
  int stage = v >> 1;
  int cc = f2 / 6, gate = (f2 % 6) >> 1, og2 = f2 & 1;
  int j = stage / 9, tap = stage % 9;
  int och = gate*64 + (oh*2 + og2)*16 + (lane & 15);
  int c = cc*32 + (lane >> 4)*8 + e;
  const float* src = (j==0) ? c1 : ((j==1) ? c2h : h2h);
  wA[idx] = f2b(src[(och*64 + c)*9 + tap]);
}

/* ---- BN partial sums ---- */
__global__ void k_bnsum(const float* __restrict__ x, float* __restrict__ part){
  int c = blockIdx.x & 63, g = blockIdx.x >> 6;
  int tid = threadIdx.x, w = tid >> 6, lane = tid & 63;
  float s = 0.f, s2 = 0.f;
  for (int im = 0; im < 4; ++im){
    const float* base = x + (((size_t)((g*4+im)*64 + c)) << 12);
    #pragma unroll
    for (int it = 0; it < 4; ++it){
      float4 v = *(const float4*)(base + (((it<<8) + tid) << 2));
      s  += v.x + v.y + v.z + v.w;
      s2 += v.x*v.x + v.y*v.y + v.z*v.z + v.w*v.w;
    }
  }
  #pragma unroll
  for (int off = 32; off > 0; off >>= 1){
    s  += __shfl_down(s,  off);
    s2 += __shfl_down(s2, off);
  }
  __shared__ float red[8];
  if (lane == 0){ red[w] = s; red[4+w] = s2; }
  __syncthreads();
  if (tid == 0){
    part[(g<<7) + c] = red[0]+red[1]+red[2]+red[3];
    part[(g<<7) + 64 + c] = red[4]+red[5]+red[6]+red[7];
  }
}

__global__ void k_bnfin(const float* __restrict__ part, const float* __restrict__ gamma,
                        const float* __restrict__ beta, float* __restrict__ scale,
                        float* __restrict__ shift){
  int c = threadIdx.x;
  float S = 0.f, S2 = 0.f;
  for (int g = 0; g < 16; ++g){ S += part[(g<<7)+c]; S2 += part[(g<<7)+64+c]; }
  const float inv = 1.f/262144.f;
  float mean = S*inv;
  float var  = S2*inv - mean*mean;
  float sc = gamma[c] * rsqrtf(var + 1e-5f);
  scale[c] = sc;
  shift[c] = beta[c] - mean*sc;
}

/* ---- BN apply -> padded bf16 [img][66][66][64]; self-haloed ---- */
__global__ void k_bnx(const float* __restrict__ x, const float* __restrict__ scale,
                      const float* __restrict__ shift, char* __restrict__ bnxp){
  int img = blockIdx.x / 66, rp = blockIdx.x % 66;
  int tid = threadIdx.x;
  char* dstrow = bnxp + (size_t)img*IMG_BYTES + (size_t)rp*8448;
  const uint4 z = {0,0,0,0};
  if (rp == 0 || rp == 65){
    for (int i = tid; i < 528; i += 256) ((uint4*)dstrow)[i] = z;
    return;
  }
  if (tid < 16)
    *(uint4*)(dstrow + (tid>>3)*(65*128) + (tid&7)*16) = z;
  int r = rp - 1;
  int col = tid & 63, cq = tid >> 6;
  const float* xb = x + (((size_t)(img*64 + cq*16)) << 12) + (r<<6) + col;
  union { u16 u[16]; uint4 v[2]; } pk;
  #pragma unroll
  for (int i = 0; i < 16; ++i){
    int c = cq*16 + i;
    pk.u[i] = f2b(xb[((size_t)i) << 12]*scale[c] + shift[c]);
  }
  char* dst = dstrow + (size_t)(col + 1)*128 + cq*32;
  *(uint4*)dst = pk.v[0];
  *(uint4*)(dst+16) = pk.v[1];
}

/* ---- fused ConvLSTM step: 256 blocks = (n, row-pair rp, oh). 512 thr =
        8 waves (wr, og2, ch). Weight DMA ring-6, paired stages, setprio,
        coalesced cstate. LDS input tile: 128 B cells with XOR chunk swizzle
        (chunk k of cell c at c*128 + ((k^(c&7))*16)). ---- */
#define STAGE_W(v) do {                                                         \
  if ((v) <= 26 && w < 4){                                                      \
    int _vj = jp + (v)/9; if (_vj >= 3) _vj -= 3;                               \
    int _vt = tp + (v)%9; if (_vt >= 9) _vt -= 9;                               \
    const char* _gs = wA + ((size_t)((_vj*9 + _vt)*2 + oh))*12288               \
                        + w*3072 + lane*16;                                     \
    char* _ls = smem + SM_RING_OFF + ((v)%6)*12288 + w*3072;                    \
    __builtin_amdgcn_global_load_lds((GASV*)(_gs),        (LASV*)(_ls),        16, 0, 0); \
    __builtin_amdgcn_global_load_lds((GASV*)(_gs + 1024), (LASV*)(_ls + 1024), 16, 0, 0); \
    __builtin_amdgcn_global_load_lds((GASV*)(_gs + 2048), (LASV*)(_ls + 2048), 16, 0, 0); \
  }                                                                             \
} while(0)

#define WAITN_BAR(N) do {                                                       \
  asm volatile("s_waitcnt vmcnt(" #N ")\n\ts_barrier" ::: "memory");            \
  __builtin_amdgcn_sched_barrier(0);                                            \
} while(0)

#define COMPUTE(u) do {                                                         \
  int tv = tp + (u)%9; if (tv >= 9) tv -= 9;                                    \
  const int kh = tv/3, kw = tv - kh*3;                                          \
  const char* ab0 = smem + SM_RING_OFF + ((u)%6)*12288 + og2*1024 + lane*16;    \
  const int c_ = (ch<<5) + kw + l15;                                            \
  const char* rowb = smem + (wr + kh)*8448 + c_*128;                            \
  _Pragma("unroll")                                                             \
  for (int cc = 0; cc < 2; ++cc){                                               \
    short8 af = *(const short8*)(ab0 + cc*6144);                                \
    short8 ao = *(const short8*)(ab0 + cc*6144 + 2048);                         \
    short8 ag = *(const short8*)(ab0 + cc*6144 + 4096);                         \
    const char* ib0 = rowb + ((((cc<<2)|l4) ^ (c_&7))<<4);                      \
    _Pragma("unroll")                                                           \
    for (int cf = 0; cf < 2; ++cf){                                             \
      short8 bf = *(const short8*)(ib0 + (cf<<11));                             \
      acc[0][cf] = __builtin_amdgcn_mfma_f32_16x16x32_bf16(af, bf, acc[0][cf], 0,0,0); \
      acc[1][cf] = __builtin_amdgcn_mfma_f32_16x16x32_bf16(ao, bf, acc[1][cf], 0,0,0); \
      acc[2][cf] = __builtin_amdgcn_mfma_f32_16x16x32_bf16(ag, bf, acc[2][cf], 0,0,0); \
    }                                                                           \
  }                                                                             \
} while(0)

__global__ __launch_bounds__(512, 1) void k_step(
    const char* __restrict__ bnxp,
    const char* __restrict__ cpad_s, const char* __restrict__ hpad_s,
    char* __restrict__ cpad_d, char* __restrict__ hpad_d,
    const char* __restrict__ wA, const float* __restrict__ b1,
    float* __restrict__ cstate, float* __restrict__ out, int t)
{
  extern __shared__ __align__(16) char smem[];
  const int tid = threadIdx.x;
  const int w = tid >> 6, lane = tid & 63;
  const int l15 = lane & 15, l4 = lane >> 4;
  const int wr = w >> 2, og2 = (w >> 1) & 1, ch = w & 1;
  const int bid = blockIdx.x;
  const int oh = bid & 1, rp = (bid >> 1) & 31, n = bid >> 6;
  const int jp = bid % 3, tp = bid % 9;

  const char* gb0 = bnxp   + (size_t)(t*4+n)*IMG_BYTES + rp*16896;
  const char* gb1 = cpad_s + (size_t)n*IMG_BYTES + rp*16896;
  const char* gb2 = hpad_s + (size_t)n*IMG_BYTES + rp*16896;

  /* cstate: coalesced [bid][tid][8] f32; t==0 -> zeros (skip poison read) */
  float* cslot = cstate + ((size_t)bid*512 + tid)*8;
  float cpv[8];
  if (t == 0){
    #pragma unroll
    for (int i = 0; i < 8; ++i) cpv[i] = 0.f;
  } else {
    f32x4 c0 = *(const f32x4*)cslot;
    f32x4 c1v = *(const f32x4*)(cslot + 4);
    cpv[0]=c0[0]; cpv[1]=c0[1]; cpv[2]=c0[2]; cpv[3]=c0[3];
    cpv[4]=c1v[0]; cpv[5]=c1v[1]; cpv[6]=c1v[2]; cpv[7]=c1v[3];
  }

  const int gc0 = ((oh<<1) + og2)*16 + l4*4;
  float bv[12];
  #pragma unroll
  for (int reg = 0; reg < 4; ++reg){
    bv[reg]   = b1[gc0+reg];
    bv[4+reg] = b1[64+gc0+reg];
    bv[8+reg] = b1[128+gc0+reg];
  }

  f32x4 acc[3][2];
  #pragma unroll
  for (int a = 0; a < 3; ++a)
    #pragma unroll
    for (int b = 0; b < 2; ++b)
      acc[a][b] = (f32x4){0.f,0.f,0.f,0.f};

  /* prologue: 4 weight stages in flight */
  STAGE_W(0); STAGE_W(1); STAGE_W(2); STAGE_W(3);

  #pragma unroll
  for (int jj = 0; jj < 3; ++jj){
    int jv = jp + jj; if (jv >= 3) jv -= 3;
    const char* gbj = (jv==0) ? gb0 : ((jv==1) ? gb1 : gb2);
    /* stage 4 input rows; XOR-swizzled chunk placement (exact i/528 split) */
    for (int i = tid; i < 2112; i += 512){
      int rr = i / 528;                 /* const-div -> magic multiply */
      int iw = i - rr*528;
      int c = iw >> 3, k = iw & 7;
      *(uint4*)(smem + rr*8448 + c*128 + ((k ^ (c&7))<<4)) =
          *(const uint4*)(gbj + rr*8448 + iw*16);
    }
    __syncthreads();   /* drains vmcnt+lgkmcnt: all issued stages resident */

    /* 4 pairs + 1 single per conv; barrier per pair (fused counted vmcnt) */
    #pragma unroll
    for (int pp = 0; pp < 4; ++pp){
      const int u = jj*9 + 2*pp;
      STAGE_W(u+4); STAGE_W(u+5);
      __builtin_amdgcn_s_setprio(1);
      COMPUTE(u);
      COMPUTE(u+1);
      __builtin_amdgcn_s_setprio(0);
      if (u == 22)      WAITN_BAR(3);
      else if (u == 24) WAITN_BAR(0);
      else              WAITN_BAR(6);
    }
    {
      const int u = jj*9 + 8;
      STAGE_W(u+4);
      __builtin_amdgcn_s_setprio(1);
      COMPUTE(u);
      __builtin_amdgcn_s_setprio(0);
    }
  }

  /* epilogue: gates; coalesced cstate write; out + bf16 h/c pad writes */
  const int r = (rp << 1) + wr;
  const size_t ob = ((size_t)((t*4+n)*64)) << 12;
  char* hrow = hpad_d + (size_t)n*IMG_BYTES + (size_t)(r+1)*8448;
  char* crow = cpad_d + (size_t)n*IMG_BYTES + (size_t)(r+1)*8448;

  float cnew[8];
  #pragma unroll
  for (int cf = 0; cf < 2; ++cf){
    const int col = (ch<<5) + (cf<<4) + l15;
    const int p = (r<<6) + col;
    union { u16 u[4]; uint2 v; } hp, cp2;
    #pragma unroll
    for (int reg = 0; reg < 4; ++reg){
      const int gc = gc0 + reg;
      float f  = sigm(acc[0][cf][reg] + bv[reg]);
      float og_ = sigm(acc[1][cf][reg] + bv[4+reg]);
      float g  = tanh_(acc[2][cf][reg] + bv[8+reg]);
      float cn = f*cpv[cf*4+reg] + (1.f-f)*g;
      float hn = og_ * tanh_(cn);
      cnew[cf*4+reg] = cn;
      out[ob + (((size_t)gc)<<12) + p] = hn;
      hp.u[reg]  = f2b(hn);
      cp2.u[reg] = f2b(cn);
    }
    *(uint2*)(hrow + (size_t)(col+1)*128 + gc0*2) = hp.v;
    *(uint2*)(crow + (size_t)(col+1)*128 + gc0*2) = cp2.v;
  }
  *(f32x4*)cslot       = (f32x4){cnew[0],cnew[1],cnew[2],cnew[3]};
  *(f32x4*)(cslot + 4) = (f32x4){cnew[4],cnew[5],cnew[6],cnew[7]};
}

extern "C" void kernel_launch(void* const* d_in, const int* in_sizes, int n_in,
                              void* d_out, int out_size, void* d_ws, size_t ws_size,
                              hipStream_t stream)
{
  (void)in_sizes; (void)n_in; (void)out_size; (void)ws_size;
  const float* x     = (const float*)d_in[0];
  const float* gamma = (const float*)d_in[1];
  const float* beta  = (const float*)d_in[2];
  const float* c1w   = (const float*)d_in[3];
  const float* c1b   = (const float*)d_in[4];
  const float* wh2h  = (const float*)d_in[5];
  const float* wc2h  = (const float*)d_in[6];
  char* ws  = (char*)d_ws;
  float* out = (float*)d_out;

  hipFuncSetAttribute(reinterpret_cast<const void*>(k_step),
                      hipFuncAttributeMaxDynamicSharedMemorySize, SMEM_TOT);

  char* hpad0 = ws + WS_HC;
  char* cpad0 = ws + WS_HC + (size_t)4*IMG_BYTES;
  char* hpad1 = ws + WS_HC + (size_t)8*IMG_BYTES;
  char* cpad1 = ws + WS_HC + (size_t)12*IMG_BYTES;

  /* zero h/c ping-pong (halos + t0 state); cstate handled by t0 branch */
  hipMemsetAsync(ws + WS_HC, 0, (size_t)16*IMG_BYTES, stream);

  k_wt<<<1296, 256, 0, stream>>>(c1w, wc2h, wh2h, (u16*)(ws + WS_WA));
  k_bnsum<<<1024, 256, 0, stream>>>(x, (float*)(ws + WS_PART));
  k_bnfin<<<1, 64, 0, stream>>>((const float*)(ws + WS_PART), gamma, beta,
                                (float*)(ws + WS_SCALE), (float*)(ws + WS_SHIFT));
  k_bnx<<<4224, 256, 0, stream>>>(x, (const float*)(ws + WS_SCALE),
                                  (const float*)(ws + WS_SHIFT), ws + WS_BNXP);
  for (int t = 0; t < 16; ++t){
    const char* cs = (t & 1) ? cpad1 : cpad0;
    const char* hs = (t & 1) ? hpad1 : hpad0;
    char* cd = (t & 1) ? cpad0 : cpad1;
    char* hd = (t & 1) ? hpad0 : hpad1;
    k_step<<<256, 512, SMEM_TOT, stream>>>(ws + WS_BNXP, cs, hs, cd, hd,
                                           ws + WS_WA, c1b,
                                           (float*)(ws + WS_CSTATE), out, t);
  }
}